// Round 21
// baseline (52.290 us; speedup 1.0000x reference)
//
#include <hip/hip_runtime.h>
#include <math.h>
#include <stdint.h>

// Problem constants (b=1, h=8, t=2048, d=64, n=32)
#define BH 8
#define NB 32
#define SS 64
#define DD 64
#define TT 2048

typedef float f32x16 __attribute__((ext_vector_type(16)));
typedef short bf16x8 __attribute__((ext_vector_type(8)));
typedef unsigned short u16;

__device__ __forceinline__ unsigned pkbf(float a, float b) {
  unsigned r;
  asm("v_cvt_pk_bf16_f32 %0, %1, %2" : "=v"(r) : "v"(a), "v"(b));
  return r;
}
__device__ __forceinline__ float exp2x(float x) {
  float r;
  asm("v_exp_f32 %0, %1" : "=v"(r) : "v"(x));
  return r;
}
__device__ __forceinline__ float log2x(float x) {
  float r;
  asm("v_log_f32 %0, %1" : "=v"(r) : "v"(x));
  return r;
}
__device__ __forceinline__ float bfhi(unsigned u16v) {
  union { unsigned u; float f; } x;
  x.u = u16v << 16;
  return x.f;
}
__device__ __forceinline__ bf16x8 pack8v(const f32x16& v, const int b) {
  union { unsigned u[4]; bf16x8 v8; } x;
  x.u[0] = pkbf(v[b + 0], v[b + 1]);
  x.u[1] = pkbf(v[b + 2], v[b + 3]);
  x.u[2] = pkbf(v[b + 4], v[b + 5]);
  x.u[3] = pkbf(v[b + 6], v[b + 7]);
  return x.v8;
}

// ---------------- Kernel 1: prep (R5-verified verbatim) -------------------
__global__ __launch_bounds__(256) void prep_kernel(
    const float* __restrict__ q, const float* __restrict__ k, const float* __restrict__ v,
    u16* __restrict__ qb, u16* __restrict__ kb, u16* __restrict__ vtb,
    float* __restrict__ qsum, float* __restrict__ ksum)
{
  __shared__ float qt[64][68];
  __shared__ float kt[64][68];
  __shared__ float vt[64][68];

  const int T = blockIdx.x;
  const int t = threadIdx.x;
  const float* qsrc = q + (size_t)T * 4096;
  const float* ksrc = k + (size_t)T * 4096;
  const float* vsrc = v + (size_t)T * 4096;

#pragma unroll
  for (int r4 = 0; r4 < 4; ++r4) {
    int f = r4 * 256 + t;
    int row = f >> 4, c4 = (f & 15) << 2;
    *(float4*)&qt[row][c4] = ((const float4*)qsrc)[f];
    *(float4*)&kt[row][c4] = ((const float4*)ksrc)[f];
    *(float4*)&vt[row][c4] = ((const float4*)vsrc)[f];
  }
  __syncthreads();

  const float qscale = 0.18033688011112042f;  // 0.125 * log2(e)

#pragma unroll
  for (int half = 0; half < 2; ++half) {
    int x = half * 256 + t;
    int c = x >> 6, lane = x & 63;
    int l31 = lane & 31, hi = lane >> 5;
    int m = c >> 2, s = c & 3;
    int row = l31 + 32 * m;
    int cb = 16 * s + 4 * hi;
    float4 a = *(const float4*)&qt[row][cb];
    float4 b = *(const float4*)&qt[row][cb + 8];
    uint4 o;
    o.x = pkbf(a.x * qscale, a.y * qscale);
    o.y = pkbf(a.z * qscale, a.w * qscale);
    o.z = pkbf(b.x * qscale, b.y * qscale);
    o.w = pkbf(b.z * qscale, b.w * qscale);
    *(uint4*)(qb + (size_t)T * 4096 + (size_t)x * 8) = o;

    float4 ka = *(const float4*)&kt[row][cb];
    float4 kb4 = *(const float4*)&kt[row][cb + 8];
    uint4 ko;
    ko.x = pkbf(ka.x, ka.y);
    ko.y = pkbf(ka.z, ka.w);
    ko.z = pkbf(kb4.x, kb4.y);
    ko.w = pkbf(kb4.z, kb4.w);
    *(uint4*)(kb + (size_t)T * 4096 + (size_t)x * 8) = ko;

    int d = l31 + 32 * m;
    int kb0 = 16 * s + 4 * hi;
    uint4 vo;
    vo.x = pkbf(vt[kb0 + 0][d], vt[kb0 + 1][d]);
    vo.y = pkbf(vt[kb0 + 2][d], vt[kb0 + 3][d]);
    vo.z = pkbf(vt[kb0 + 8][d], vt[kb0 + 9][d]);
    vo.w = pkbf(vt[kb0 + 10][d], vt[kb0 + 11][d]);
    *(uint4*)(vtb + (size_t)T * 4096 + (size_t)x * 8) = vo;
  }

  // bucket column sums for the sort-net
  if (t < 64) {
    float s = 0.f;
#pragma unroll 8
    for (int r = 0; r < 64; ++r) s += qt[r][t];
    qsum[T * 64 + t] = s;
  } else if (t < 128) {
    int c = t - 64;
    float s = 0.f;
#pragma unroll 8
    for (int r = 0; r < 64; ++r) s += kt[r][c];
    ksum[T * 64 + c] = s;
  }
}

// ---------------- Kernel 2: MFMA attention + inline Sinkhorn --------------
// 256 blocks x 512 threads, bh = bid&7. 8 waves; wave w owns j = w + 8*jj
// (4 iters) and computes BOTH q-blocks per j, reusing in-register kA/vB
// (halves kA/vB L2 traffic vs R15's n=w&1 split). Sinkhorn/self/softmax
// math byte-reused from R15/R20 (maxless softmax BANNED: failed R3/R18).
__global__ __launch_bounds__(512) void attn_kernel(
    const u16* __restrict__ qb, const u16* __restrict__ kb,
    const u16* __restrict__ vtb, const float* __restrict__ qsum,
    const float* __restrict__ ksum, const float* __restrict__ gu,
    float* __restrict__ out)
{
  __shared__ __align__(16) unsigned char smem[36864];
  // attn-phase aliases
  float (*redh)[32][68] = (float (*)[32][68])smem;             // 4 bufs, 34816 B
  float (*cbufN)[8][32] = (float (*)[8][32])(smem + 34816);    // [2][8][32], 2048 B
  // sinkhorn-phase aliases (dead before first redh write; cbufN disjoint)
  float* qs = (float*)smem;          // [32][65]
  float* ks = qs + 32 * 65;          // [32][65]
  float* LT = ks + 32 * 65;          // [32][33]

  const int bh  = blockIdx.x & 7;
  const int i   = blockIdx.x >> 3;
  const int t   = threadIdx.x;
  const int w   = t >> 6;            // 0..7 = owned j residue
  const int lane = t & 63;
  const int l31 = lane & 31;
  const int hi  = lane >> 5;

  const u16* qtile = qb + ((size_t)(bh * NB + i)) * 4096;
  const u16* kbh   = kb + (size_t)bh * NB * 4096;
  const u16* vbh   = vtb + (size_t)bh * NB * 4096;

#define LOADG(dst, base)                                                      \
  {                                                                           \
    _Pragma("unroll") for (int m = 0; m < 2; ++m)                             \
    _Pragma("unroll") for (int s = 0; s < 4; ++s)                             \
      dst[m][s] = *(const bf16x8*)((base) + ((size_t)((m * 4 + s) * 64 + lane)) * 8); \
  }

  // issue all pre-sinkhorn loads now; latency hides under sinkhorn compute
  bf16x8 qB[2][4];
#pragma unroll
  for (int nn = 0; nn < 2; ++nn)
#pragma unroll
    for (int s = 0; s < 4; ++s)
      qB[nn][s] = *(const bf16x8*)(qtile + ((size_t)((nn * 4 + s) * 64 + lane)) * 8);
  bf16x8 kA[2][4], vB[2][4], kAi[2][4];
  LOADG(kA, kbh + (size_t)w * 4096);
  LOADG(vB, vbh + (size_t)w * 4096);
  LOADG(kAi, kbh + (size_t)i * 4096);

  // ---- inline per-head Sinkhorn (R15/R20-verified region) ----
  float rij4[4];
  {
    const float L2E = 1.4426950408889634f;
    const float LN2 = 0.6931471805599453f;

    if (t < 256) {
      int idx = t * 8;
      float4 a = *(const float4*)(qsum + bh * 2048 + idx);
      float4 b = *(const float4*)(qsum + bh * 2048 + idx + 4);
      float4 c = *(const float4*)(ksum + bh * 2048 + idx);
      float4 d = *(const float4*)(ksum + bh * 2048 + idx + 4);
      int bkt = idx >> 6, e = idx & 63;
      float* qd = qs + bkt * 65 + e;
      qd[0] = a.x; qd[1] = a.y; qd[2] = a.z; qd[3] = a.w;
      qd[4] = b.x; qd[5] = b.y; qd[6] = b.z; qd[7] = b.w;
      float* kd = ks + bkt * 65 + e;
      kd[0] = c.x; kd[1] = c.y; kd[2] = c.z; kd[3] = c.w;
      kd[4] = d.x; kd[5] = d.y; kd[6] = d.z; kd[7] = d.w;
    }
    __syncthreads();

    // logits via hi/lo-split bf16 MFMA (wave 0 only, f32-accurate)
    if (t < 64) {
      bf16x8 qh[4], ql[4], kh[4], kl[4];
#pragma unroll
      for (int s = 0; s < 4; ++s) {
        const int base = 16 * s + 4 * hi;
        float qv[8], kv[8];
#pragma unroll
        for (int x = 0; x < 8; ++x) {
          int off = (x & 3) + 8 * (x >> 2);
          qv[x] = qs[l31 * 65 + base + off];
          kv[x] = ks[l31 * 65 + base + off];
        }
        union { unsigned u[4]; bf16x8 v8; } qhh, qll, khh, kll;
#pragma unroll
        for (int p = 0; p < 4; ++p) {
          unsigned hq = pkbf(qv[2 * p], qv[2 * p + 1]);
          qhh.u[p] = hq;
          qll.u[p] = pkbf(qv[2 * p] - bfhi(hq & 0xffffu),
                          qv[2 * p + 1] - bfhi(hq >> 16));
          unsigned hk = pkbf(kv[2 * p], kv[2 * p + 1]);
          khh.u[p] = hk;
          kll.u[p] = pkbf(kv[2 * p] - bfhi(hk & 0xffffu),
                          kv[2 * p + 1] - bfhi(hk >> 16));
        }
        qh[s] = qhh.v8; ql[s] = qll.v8;
        kh[s] = khh.v8; kl[s] = kll.v8;
      }
      f32x16 accL;
#pragma unroll
      for (int r = 0; r < 16; ++r) accL[r] = 0.f;
#pragma unroll
      for (int s = 0; s < 4; ++s) {
        accL = __builtin_amdgcn_mfma_f32_32x32x16_bf16(qh[s], kh[s], accL, 0, 0, 0);
        accL = __builtin_amdgcn_mfma_f32_32x32x16_bf16(qh[s], kl[s], accL, 0, 0, 0);
        accL = __builtin_amdgcn_mfma_f32_32x32x16_bf16(ql[s], kh[s], accL, 0, 0, 0);
      }
#pragma unroll
      for (int r = 0; r < 16; ++r) {
        int ii = (r & 3) + 8 * (r >> 2) + 4 * hi;
        float L = accL[r] * 0.125f;
        float u = gu[bh * 1024 + ii * 32 + l31];
        float il = log2x(u + 1e-6f) * LN2;
        float gg = -(log2x(-il + 1e-6f) * LN2);
        float lr = log2x(fmaxf(L, 0.f) + 1e-6f) * LN2;
        LT[ii * 33 + l31] = (lr + gg) * (1.0f / 0.75f);
      }
    }
    __syncthreads();

    // wave-0 iterations: lane l holds 16 values (half row / half column)
    if (t < 64) {
      const int l = t;
      const int half16 = (l & 1) * 16;
      const int major = l >> 1;
      float r[16];
#pragma unroll
      for (int x = 0; x < 16; ++x) r[x] = LT[major * 33 + half16 + x];

      for (int it = 0; it < 7; ++it) {
        {
          float e[16];
#pragma unroll
          for (int x = 0; x < 16; ++x) e[x] = exp2x(r[x] * L2E);
#pragma unroll
          for (int off = 8; off > 0; off >>= 1)
#pragma unroll
            for (int x = 0; x < off; ++x) e[x] += e[x + off];
          float s = e[0] + __shfl_xor(e[0], 1, 64);
          float L = log2x(fmaxf(s, 1e-30f)) * LN2;
#pragma unroll
          for (int x = 0; x < 16; ++x) r[x] -= L;
        }
#pragma unroll
        for (int x = 0; x < 16; ++x) LT[major * 33 + half16 + x] = r[x];
#pragma unroll
        for (int x = 0; x < 16; ++x) r[x] = LT[(half16 + x) * 33 + major];
        {
          float e[16];
#pragma unroll
          for (int x = 0; x < 16; ++x) e[x] = exp2x(r[x] * L2E);
#pragma unroll
          for (int off = 8; off > 0; off >>= 1)
#pragma unroll
            for (int x = 0; x < off; ++x) e[x] += e[x + off];
          float s = e[0] + __shfl_xor(e[0], 1, 64);
          float L = log2x(fmaxf(s, 1e-30f)) * LN2;
#pragma unroll
          for (int x = 0; x < 16; ++x) r[x] -= L;
        }
        if (it < 6) {
#pragma unroll
          for (int x = 0; x < 16; ++x) LT[(half16 + x) * 33 + major] = r[x];
#pragma unroll
          for (int x = 0; x < 16; ++x) r[x] = LT[major * 33 + half16 + x];
        }
      }

#pragma unroll
      for (int x = 0; x < 16; ++x) {
        float R = exp2x(r[x] * L2E);
        LT[(half16 + x) * 33 + major] = (R > 1e-3f) ? R : 0.f;  // LT[r][c] = R
      }
    }
    __syncthreads();

#pragma unroll
    for (int jj = 0; jj < 4; ++jj) rij4[jj] = LT[i * 33 + w + 8 * jj];
  }

  // ---- self phase: both q-blocks, kAi reused (R15-verified math) ----
  float m0v[2], S0v[2];
  bf16x8 psA[2][4];
#pragma unroll
  for (int nn = 0; nn < 2; ++nn) {
    f32x16 aS0, aS1;
#pragma unroll
    for (int r = 0; r < 16; ++r) { aS0[r] = 0.f; aS1[r] = 0.f; }
#pragma unroll
    for (int s = 0; s < 4; ++s) {
      aS0 = __builtin_amdgcn_mfma_f32_32x32x16_bf16(kAi[0][s], qB[nn][s], aS0, 0, 0, 0);
      aS1 = __builtin_amdgcn_mfma_f32_32x32x16_bf16(kAi[1][s], qB[nn][s], aS1, 0, 0, 0);
    }
    float mx[16];
#pragma unroll
    for (int r = 0; r < 16; ++r) mx[r] = fmaxf(aS0[r], aS1[r]);
#pragma unroll
    for (int off = 8; off > 0; off >>= 1)
#pragma unroll
      for (int r = 0; r < off; ++r) mx[r] = fmaxf(mx[r], mx[r + off]);
    float mm = fmaxf(mx[0], __shfl_xor(mx[0], 32, 64));
#pragma unroll
    for (int r = 0; r < 16; ++r) { aS0[r] = exp2x(aS0[r] - mm); aS1[r] = exp2x(aS1[r] - mm); }
    float sm[16];
#pragma unroll
    for (int r = 0; r < 16; ++r) sm[r] = aS0[r] + aS1[r];
#pragma unroll
    for (int off = 8; off > 0; off >>= 1)
#pragma unroll
      for (int r = 0; r < off; ++r) sm[r] += sm[r + off];
    S0v[nn] = sm[0] + __shfl_xor(sm[0], 32, 64);
    m0v[nn] = mm;
    psA[nn][0] = pack8v(aS0, 0);
    psA[nn][1] = pack8v(aS0, 8);
    psA[nn][2] = pack8v(aS1, 0);
    psA[nn][3] = pack8v(aS1, 8);
  }

  f32x16 outAcc[2][2];
#pragma unroll
  for (int nn = 0; nn < 2; ++nn)
#pragma unroll
    for (int ne = 0; ne < 2; ++ne)
#pragma unroll
      for (int e = 0; e < 16; ++e) outAcc[nn][ne][e] = 0.f;
  float cacc[2] = {0.f, 0.f};

  // ---- j loop: 4 iters, both n per j reusing in-register kA/vB ----
#pragma unroll
  for (int jj = 0; jj < 4; ++jj) {
    const int j = w + 8 * jj;
    const float rij = rij4[jj];

#pragma unroll
    for (int nn = 0; nn < 2; ++nn) {
      f32x16 a0, a1;
#pragma unroll
      for (int r = 0; r < 16; ++r) { a0[r] = 0.f; a1[r] = 0.f; }
      __builtin_amdgcn_s_setprio(1);
#pragma unroll
      for (int s = 0; s < 4; ++s) {
        a0 = __builtin_amdgcn_mfma_f32_32x32x16_bf16(kA[0][s], qB[nn][s], a0, 0, 0, 0);
        a1 = __builtin_amdgcn_mfma_f32_32x32x16_bf16(kA[1][s], qB[nn][s], a1, 0, 0, 0);
      }
      __builtin_amdgcn_s_setprio(0);

      if (nn == 1 && jj < 3) LOADG(kA, kbh + (size_t)(j + 8) * 4096);  // kA dead

      float mx[16];
#pragma unroll
      for (int r = 0; r < 16; ++r) mx[r] = fmaxf(a0[r], a1[r]);
#pragma unroll
      for (int off = 8; off > 0; off >>= 1)
#pragma unroll
        for (int r = 0; r < off; ++r) mx[r] = fmaxf(mx[r], mx[r + off]);
      float mc = fmaxf(mx[0], __shfl_xor(mx[0], 32, 64));
      float mj = fmaxf(m0v[nn], mc);
#pragma unroll
      for (int r = 0; r < 16; ++r) { a0[r] = exp2x(a0[r] - mj); a1[r] = exp2x(a1[r] - mj); }
      float sm[16];
#pragma unroll
      for (int r = 0; r < 16; ++r) sm[r] = a0[r] + a1[r];
#pragma unroll
      for (int off = 8; off > 0; off >>= 1)
#pragma unroll
        for (int r = 0; r < off; ++r) sm[r] += sm[r + off];
      float ssum = sm[0] + __shfl_xor(sm[0], 32, 64);
      float e0 = exp2x(m0v[nn] - mj);
      float den = S0v[nn] * e0 + ssum;
      float inv = rij / den;
      cacc[nn] += e0 * inv;
#pragma unroll
      for (int r = 0; r < 16; ++r) { a0[r] *= inv; a1[r] *= inv; }

      __builtin_amdgcn_s_setprio(1);
#pragma unroll
      for (int s = 0; s < 4; ++s) {
        bf16x8 wf = (s < 2) ? pack8v(a0, 8 * (s & 1)) : pack8v(a1, 8 * (s & 1));
        outAcc[nn][0] = __builtin_amdgcn_mfma_f32_32x32x16_bf16(wf, vB[0][s], outAcc[nn][0], 0, 0, 0);
        outAcc[nn][1] = __builtin_amdgcn_mfma_f32_32x32x16_bf16(wf, vB[1][s], outAcc[nn][1], 0, 0, 0);
      }
      __builtin_amdgcn_s_setprio(0);

      if (nn == 1 && jj < 3) LOADG(vB, vbh + (size_t)(j + 8) * 4096);  // vB dead
    }
  }

  // ---- self term: out += cacc(row) * psA @ V_i (per n, U freed per n) ----
  {
    const u16* vib = vbh + (size_t)i * 4096;
    bf16x8 vBi[2][4];
    LOADG(vBi, vib);
    if (hi == 0) {
      cbufN[0][w][l31] = cacc[0];
      cbufN[1][w][l31] = cacc[1];
    }
    __syncthreads();
#pragma unroll
    for (int nn = 0; nn < 2; ++nn) {
      f32x16 U0, U1;
#pragma unroll
      for (int e = 0; e < 16; ++e) { U0[e] = 0.f; U1[e] = 0.f; }
#pragma unroll
      for (int s = 0; s < 4; ++s) {
        U0 = __builtin_amdgcn_mfma_f32_32x32x16_bf16(psA[nn][s], vBi[0][s], U0, 0, 0, 0);
        U1 = __builtin_amdgcn_mfma_f32_32x32x16_bf16(psA[nn][s], vBi[1][s], U1, 0, 0, 0);
      }
#pragma unroll
      for (int r = 0; r < 16; ++r) {
        int row = (r & 3) + 8 * (r >> 2) + 4 * hi;
        float cr = cbufN[nn][w][row];
        outAcc[nn][0][r] += U0[r] * cr;
        outAcc[nn][1][r] += U1[r] * cr;
      }
    }
  }

  // ---- sequential per-n 8-wave reduction trees (reuse one 4-buf region) --
#define RED_W2(buf, nn)                                                    \
  {                                                                        \
    _Pragma("unroll") for (int ne = 0; ne < 2; ++ne)                       \
    _Pragma("unroll") for (int r = 0; r < 16; ++r) {                       \
      int row = (r & 3) + 8 * (r >> 2) + 4 * hi;                           \
      (buf)[row][l31 + 32 * ne] = outAcc[nn][ne][r];                       \
    }                                                                      \
  }
#define RED_A2(buf, nn)                                                    \
  {                                                                        \
    _Pragma("unroll") for (int ne = 0; ne < 2; ++ne)                       \
    _Pragma("unroll") for (int r = 0; r < 16; ++r) {                       \
      int row = (r & 3) + 8 * (r >> 2) + 4 * hi;                           \
      outAcc[nn][ne][r] += (buf)[row][l31 + 32 * ne];                      \
    }                                                                      \
  }

#pragma unroll
  for (int nn = 0; nn < 2; ++nn) {
    if (w >= 4) RED_W2(redh[w - 4], nn);
    __syncthreads();
    if (w < 4) RED_A2(redh[w], nn);
    __syncthreads();
    if (w == 2 || w == 3) RED_W2(redh[w - 2], nn);
    __syncthreads();
    if (w < 2) RED_A2(redh[w], nn);
    __syncthreads();
    if (w == 1) RED_W2(redh[0], nn);
    __syncthreads();
    if (w == 0) {
      RED_A2(redh[0], nn);
      RED_W2(redh[0], nn);
    }
    __syncthreads();

    // coalesced store of this q-half (32 rows x 64 cols, 512 x float4)
    {
      int row = t >> 4;            // 0..31
      int col0 = (t & 15) * 4;
      float4 a = *(const float4*)&redh[0][row][col0];
      float* ob = out + ((size_t)bh * TT + i * SS + nn * 32 + row) * DD + col0;
      *(float4*)ob = a;
    }
    if (nn == 0) __syncthreads();  // redh reused by nn=1 tree
  }
#undef LOADG
#undef RED_W2
#undef RED_A2
}

extern "C" void kernel_launch(void* const* d_in, const int* in_sizes, int n_in,
                              void* d_out, int out_size, void* d_ws, size_t ws_size,
                              hipStream_t stream) {
  (void)in_sizes; (void)n_in; (void)out_size; (void)ws_size;
  const float* q  = (const float*)d_in[0];
  const float* k  = (const float*)d_in[1];
  const float* v  = (const float*)d_in[2];
  const float* gu = (const float*)d_in[3];
  float* out = (float*)d_out;

  char* wsb = (char*)d_ws;
  u16* qb   = (u16*)(wsb);
  u16* kb   = (u16*)(wsb + (1 << 21));
  u16* vtb  = (u16*)(wsb + (2 << 21));
  float* qsum = (float*)(wsb + (3 << 21));
  float* ksum = (float*)(wsb + (3 << 21) + (1 << 16));

  prep_kernel<<<256, 256, 0, stream>>>(q, k, v, qb, kb, vtb, qsum, ksum);
  attn_kernel<<<BH * NB, 512, 0, stream>>>(qb, kb, vtb, qsum, ksum, gu, out);
}

// Round 22
// 32.575 us; speedup vs baseline: 1.6052x; 1.6052x over previous
//
#include <hip/hip_runtime.h>
#include <math.h>
#include <stdint.h>

// Problem constants (b=1, h=8, t=2048, d=64, n=32)
#define BH 8
#define NB 32
#define SS 64
#define DD 64
#define TT 2048

typedef float f32x16 __attribute__((ext_vector_type(16)));
typedef short bf16x8 __attribute__((ext_vector_type(8)));
typedef unsigned short u16;

__device__ __forceinline__ unsigned pkbf(float a, float b) {
  unsigned r;
  asm("v_cvt_pk_bf16_f32 %0, %1, %2" : "=v"(r) : "v"(a), "v"(b));
  return r;
}
__device__ __forceinline__ float exp2x(float x) {
  float r;
  asm("v_exp_f32 %0, %1" : "=v"(r) : "v"(x));
  return r;
}
__device__ __forceinline__ float log2x(float x) {
  float r;
  asm("v_log_f32 %0, %1" : "=v"(r) : "v"(x));
  return r;
}
__device__ __forceinline__ float bfhi(unsigned u16v) {
  union { unsigned u; float f; } x;
  x.u = u16v << 16;
  return x.f;
}
__device__ __forceinline__ bf16x8 pack8v(const f32x16& v, const int b) {
  union { unsigned u[4]; bf16x8 v8; } x;
  x.u[0] = pkbf(v[b + 0], v[b + 1]);
  x.u[1] = pkbf(v[b + 2], v[b + 3]);
  x.u[2] = pkbf(v[b + 4], v[b + 5]);
  x.u[3] = pkbf(v[b + 6], v[b + 7]);
  return x.v8;
}

// ---------------- Kernel 1: prep (R5-verified verbatim) -------------------
__global__ __launch_bounds__(256) void prep_kernel(
    const float* __restrict__ q, const float* __restrict__ k, const float* __restrict__ v,
    u16* __restrict__ qb, u16* __restrict__ kb, u16* __restrict__ vtb,
    float* __restrict__ qsum, float* __restrict__ ksum)
{
  __shared__ float qt[64][68];
  __shared__ float kt[64][68];
  __shared__ float vt[64][68];

  const int T = blockIdx.x;
  const int t = threadIdx.x;
  const float* qsrc = q + (size_t)T * 4096;
  const float* ksrc = k + (size_t)T * 4096;
  const float* vsrc = v + (size_t)T * 4096;

#pragma unroll
  for (int r4 = 0; r4 < 4; ++r4) {
    int f = r4 * 256 + t;
    int row = f >> 4, c4 = (f & 15) << 2;
    *(float4*)&qt[row][c4] = ((const float4*)qsrc)[f];
    *(float4*)&kt[row][c4] = ((const float4*)ksrc)[f];
    *(float4*)&vt[row][c4] = ((const float4*)vsrc)[f];
  }
  __syncthreads();

  const float qscale = 0.18033688011112042f;  // 0.125 * log2(e)

#pragma unroll
  for (int half = 0; half < 2; ++half) {
    int x = half * 256 + t;
    int c = x >> 6, lane = x & 63;
    int l31 = lane & 31, hi = lane >> 5;
    int m = c >> 2, s = c & 3;
    int row = l31 + 32 * m;
    int cb = 16 * s + 4 * hi;
    float4 a = *(const float4*)&qt[row][cb];
    float4 b = *(const float4*)&qt[row][cb + 8];
    uint4 o;
    o.x = pkbf(a.x * qscale, a.y * qscale);
    o.y = pkbf(a.z * qscale, a.w * qscale);
    o.z = pkbf(b.x * qscale, b.y * qscale);
    o.w = pkbf(b.z * qscale, b.w * qscale);
    *(uint4*)(qb + (size_t)T * 4096 + (size_t)x * 8) = o;

    float4 ka = *(const float4*)&kt[row][cb];
    float4 kb4 = *(const float4*)&kt[row][cb + 8];
    uint4 ko;
    ko.x = pkbf(ka.x, ka.y);
    ko.y = pkbf(ka.z, ka.w);
    ko.z = pkbf(kb4.x, kb4.y);
    ko.w = pkbf(kb4.z, kb4.w);
    *(uint4*)(kb + (size_t)T * 4096 + (size_t)x * 8) = ko;

    int d = l31 + 32 * m;
    int kb0 = 16 * s + 4 * hi;
    uint4 vo;
    vo.x = pkbf(vt[kb0 + 0][d], vt[kb0 + 1][d]);
    vo.y = pkbf(vt[kb0 + 2][d], vt[kb0 + 3][d]);
    vo.z = pkbf(vt[kb0 + 8][d], vt[kb0 + 9][d]);
    vo.w = pkbf(vt[kb0 + 10][d], vt[kb0 + 11][d]);
    *(uint4*)(vtb + (size_t)T * 4096 + (size_t)x * 8) = vo;
  }

  // bucket column sums for the sort-net
  if (t < 64) {
    float s = 0.f;
#pragma unroll 8
    for (int r = 0; r < 64; ++r) s += qt[r][t];
    qsum[T * 64 + t] = s;
  } else if (t < 128) {
    int c = t - 64;
    float s = 0.f;
#pragma unroll 8
    for (int r = 0; r < 64; ++r) s += kt[r][c];
    ksum[T * 64 + c] = s;
  }
}

// ---------------- Kernel 2: MFMA attention + inline Sinkhorn --------------
// R15/R20-verified best (32.9 us, reproduced twice): 256 blocks x 512
// threads, bh = bid&7 (XCD locality), 8 waves; wave w: n = w&1 (q-block),
// g = w>>1 (j = g + 4*jj, 8 iters). Inline per-head Sinkhorn: MFMA
// hi/lo-split logits init + wave64 16-vals/lane register iterations.
// Max-subtracted softmax (maxless BANNED: failed R3/R18). Register-pressure
// levers exhausted: R16/R19/R21 all spilled past the 128-VGPR boundary,
// R17 duplicated fixed costs. VGPR 124 @ 2 waves/SIMD is the sweet spot.
__global__ __launch_bounds__(512) void attn_kernel(
    const u16* __restrict__ qb, const u16* __restrict__ kb,
    const u16* __restrict__ vtb, const float* __restrict__ qsum,
    const float* __restrict__ ksum, const float* __restrict__ gu,
    float* __restrict__ out)
{
  __shared__ __align__(16) unsigned char smem[35840];
  // attn-phase aliases
  float (*redh)[2][32][68] = (float (*)[2][32][68])smem;       // bytes 0..34815
  float (*cbuf)[32] = (float (*)[32])(smem + 34816);           // bytes 34816..35839
  // sinkhorn-phase aliases (dead before first redh write; cbuf disjoint)
  float* qs = (float*)smem;          // [32][65]
  float* ks = qs + 32 * 65;          // [32][65]
  float* LT = ks + 32 * 65;          // [32][33]

  const int bh  = blockIdx.x & 7;
  const int i   = blockIdx.x >> 3;
  const int t   = threadIdx.x;
  const int w   = t >> 6;
  const int n   = w & 1;
  const int g   = w >> 1;
  const int lane = t & 63;
  const int l31 = lane & 31;
  const int hi  = lane >> 5;

  const u16* qtile = qb + ((size_t)(bh * NB + i)) * 4096;
  const u16* kbh   = kb + (size_t)bh * NB * 4096;
  const u16* vbh   = vtb + (size_t)bh * NB * 4096;

#define LOADG(dst, base)                                                      \
  {                                                                           \
    _Pragma("unroll") for (int m = 0; m < 2; ++m)                             \
    _Pragma("unroll") for (int s = 0; s < 4; ++s)                             \
      dst[m][s] = *(const bf16x8*)((base) + ((size_t)((m * 4 + s) * 64 + lane)) * 8); \
  }

  // issue all pre-sinkhorn loads now; latency hides under sinkhorn compute
  bf16x8 qB[4];
#pragma unroll
  for (int s = 0; s < 4; ++s)
    qB[s] = *(const bf16x8*)(qtile + ((size_t)((n * 4 + s) * 64 + lane)) * 8);
  bf16x8 kA[2][4], vB[2][4], kAi[2][4];
  LOADG(kA, kbh + (size_t)g * 4096);
  LOADG(vB, vbh + (size_t)g * 4096);
  LOADG(kAi, kbh + (size_t)i * 4096);

  // ---- inline per-head Sinkhorn ----
  float rij8[8];
  {
    const float L2E = 1.4426950408889634f;
    const float LN2 = 0.6931471805599453f;

    if (t < 256) {
      int idx = t * 8;
      float4 a = *(const float4*)(qsum + bh * 2048 + idx);
      float4 b = *(const float4*)(qsum + bh * 2048 + idx + 4);
      float4 c = *(const float4*)(ksum + bh * 2048 + idx);
      float4 d = *(const float4*)(ksum + bh * 2048 + idx + 4);
      int bkt = idx >> 6, e = idx & 63;
      float* qd = qs + bkt * 65 + e;
      qd[0] = a.x; qd[1] = a.y; qd[2] = a.z; qd[3] = a.w;
      qd[4] = b.x; qd[5] = b.y; qd[6] = b.z; qd[7] = b.w;
      float* kd = ks + bkt * 65 + e;
      kd[0] = c.x; kd[1] = c.y; kd[2] = c.z; kd[3] = c.w;
      kd[4] = d.x; kd[5] = d.y; kd[6] = d.z; kd[7] = d.w;
    }
    __syncthreads();

    // logits via hi/lo-split bf16 MFMA (wave 0 only, f32-accurate)
    if (t < 64) {
      bf16x8 qh[4], ql[4], kh[4], kl[4];
#pragma unroll
      for (int s = 0; s < 4; ++s) {
        const int base = 16 * s + 4 * hi;
        float qv[8], kv[8];
#pragma unroll
        for (int x = 0; x < 8; ++x) {
          int off = (x & 3) + 8 * (x >> 2);
          qv[x] = qs[l31 * 65 + base + off];
          kv[x] = ks[l31 * 65 + base + off];
        }
        union { unsigned u[4]; bf16x8 v8; } qhh, qll, khh, kll;
#pragma unroll
        for (int p = 0; p < 4; ++p) {
          unsigned hq = pkbf(qv[2 * p], qv[2 * p + 1]);
          qhh.u[p] = hq;
          qll.u[p] = pkbf(qv[2 * p] - bfhi(hq & 0xffffu),
                          qv[2 * p + 1] - bfhi(hq >> 16));
          unsigned hk = pkbf(kv[2 * p], kv[2 * p + 1]);
          khh.u[p] = hk;
          kll.u[p] = pkbf(kv[2 * p] - bfhi(hk & 0xffffu),
                          kv[2 * p + 1] - bfhi(hk >> 16));
        }
        qh[s] = qhh.v8; ql[s] = qll.v8;
        kh[s] = khh.v8; kl[s] = kll.v8;
      }
      f32x16 accL;
#pragma unroll
      for (int r = 0; r < 16; ++r) accL[r] = 0.f;
#pragma unroll
      for (int s = 0; s < 4; ++s) {
        accL = __builtin_amdgcn_mfma_f32_32x32x16_bf16(qh[s], kh[s], accL, 0, 0, 0);
        accL = __builtin_amdgcn_mfma_f32_32x32x16_bf16(qh[s], kl[s], accL, 0, 0, 0);
        accL = __builtin_amdgcn_mfma_f32_32x32x16_bf16(ql[s], kh[s], accL, 0, 0, 0);
      }
#pragma unroll
      for (int r = 0; r < 16; ++r) {
        int ii = (r & 3) + 8 * (r >> 2) + 4 * hi;
        float L = accL[r] * 0.125f;
        float u = gu[bh * 1024 + ii * 32 + l31];
        float il = log2x(u + 1e-6f) * LN2;          // ln(u+eps)
        float gg = -(log2x(-il + 1e-6f) * LN2);     // -ln(-ln(u+eps)+eps)
        float lr = log2x(fmaxf(L, 0.f) + 1e-6f) * LN2;
        LT[ii * 33 + l31] = (lr + gg) * (1.0f / 0.75f);
      }
    }
    __syncthreads();

    // wave-0 iterations: lane l holds 16 values (half row / half column)
    if (t < 64) {
      const int l = t;
      const int half16 = (l & 1) * 16;
      const int major = l >> 1;
      float r[16];
#pragma unroll
      for (int x = 0; x < 16; ++x) r[x] = LT[major * 33 + half16 + x];

      for (int it = 0; it < 7; ++it) {
        {
          float e[16];
#pragma unroll
          for (int x = 0; x < 16; ++x) e[x] = exp2x(r[x] * L2E);
#pragma unroll
          for (int off = 8; off > 0; off >>= 1)
#pragma unroll
            for (int x = 0; x < off; ++x) e[x] += e[x + off];
          float s = e[0] + __shfl_xor(e[0], 1, 64);
          float L = log2x(fmaxf(s, 1e-30f)) * LN2;
#pragma unroll
          for (int x = 0; x < 16; ++x) r[x] -= L;
        }
#pragma unroll
        for (int x = 0; x < 16; ++x) LT[major * 33 + half16 + x] = r[x];
#pragma unroll
        for (int x = 0; x < 16; ++x) r[x] = LT[(half16 + x) * 33 + major];
        {
          float e[16];
#pragma unroll
          for (int x = 0; x < 16; ++x) e[x] = exp2x(r[x] * L2E);
#pragma unroll
          for (int off = 8; off > 0; off >>= 1)
#pragma unroll
            for (int x = 0; x < off; ++x) e[x] += e[x + off];
          float s = e[0] + __shfl_xor(e[0], 1, 64);
          float L = log2x(fmaxf(s, 1e-30f)) * LN2;
#pragma unroll
          for (int x = 0; x < 16; ++x) r[x] -= L;
        }
        if (it < 6) {
#pragma unroll
          for (int x = 0; x < 16; ++x) LT[(half16 + x) * 33 + major] = r[x];
#pragma unroll
          for (int x = 0; x < 16; ++x) r[x] = LT[major * 33 + half16 + x];
        }
      }

#pragma unroll
      for (int x = 0; x < 16; ++x) {
        float R = exp2x(r[x] * L2E);
        LT[(half16 + x) * 33 + major] = (R > 1e-3f) ? R : 0.f;  // LT[r][c] = R
      }
    }
    __syncthreads();

#pragma unroll
    for (int jj = 0; jj < 8; ++jj) rij8[jj] = LT[i * 33 + g + 4 * jj];
  }

  // ---- self phase: S_self^T, m0, S0, psA (R4/R5-verified) ----
  float m0, S0;
  bf16x8 psA[4];
  {
    f32x16 aS0, aS1;
#pragma unroll
    for (int r = 0; r < 16; ++r) { aS0[r] = 0.f; aS1[r] = 0.f; }
#pragma unroll
    for (int s = 0; s < 4; ++s) {
      aS0 = __builtin_amdgcn_mfma_f32_32x32x16_bf16(kAi[0][s], qB[s], aS0, 0, 0, 0);
      aS1 = __builtin_amdgcn_mfma_f32_32x32x16_bf16(kAi[1][s], qB[s], aS1, 0, 0, 0);
    }
    float mx[16];
#pragma unroll
    for (int r = 0; r < 16; ++r) mx[r] = fmaxf(aS0[r], aS1[r]);
#pragma unroll
    for (int off = 8; off > 0; off >>= 1)
#pragma unroll
      for (int r = 0; r < off; ++r) mx[r] = fmaxf(mx[r], mx[r + off]);
    float mm = fmaxf(mx[0], __shfl_xor(mx[0], 32, 64));
#pragma unroll
    for (int r = 0; r < 16; ++r) { aS0[r] = exp2x(aS0[r] - mm); aS1[r] = exp2x(aS1[r] - mm); }
    float sm[16];
#pragma unroll
    for (int r = 0; r < 16; ++r) sm[r] = aS0[r] + aS1[r];
#pragma unroll
    for (int off = 8; off > 0; off >>= 1)
#pragma unroll
      for (int r = 0; r < off; ++r) sm[r] += sm[r + off];
    S0 = sm[0] + __shfl_xor(sm[0], 32, 64);
    m0 = mm;
    psA[0] = pack8v(aS0, 0);
    psA[1] = pack8v(aS0, 8);
    psA[2] = pack8v(aS1, 0);
    psA[3] = pack8v(aS1, 8);
  }

  f32x16 outAcc[2];
#pragma unroll
  for (int nv = 0; nv < 2; ++nv)
#pragma unroll
    for (int e = 0; e < 16; ++e) outAcc[nv][e] = 0.f;
  float cacc = 0.f;

  // ---- j loop: 8 barrier-free iterations, direct L2, reg prefetch ----
#pragma unroll
  for (int jj = 0; jj < 8; ++jj) {
    const int j = g + 4 * jj;
    const float rij = rij8[jj];

    f32x16 a0, a1;
#pragma unroll
    for (int r = 0; r < 16; ++r) { a0[r] = 0.f; a1[r] = 0.f; }
    __builtin_amdgcn_s_setprio(1);
#pragma unroll
    for (int s = 0; s < 4; ++s) {
      a0 = __builtin_amdgcn_mfma_f32_32x32x16_bf16(kA[0][s], qB[s], a0, 0, 0, 0);
      a1 = __builtin_amdgcn_mfma_f32_32x32x16_bf16(kA[1][s], qB[s], a1, 0, 0, 0);
    }
    __builtin_amdgcn_s_setprio(0);

    if (jj < 7) LOADG(kA, kbh + (size_t)(j + 4) * 4096);  // kA dead: prefetch

    float mx[16];
#pragma unroll
    for (int r = 0; r < 16; ++r) mx[r] = fmaxf(a0[r], a1[r]);
#pragma unroll
    for (int off = 8; off > 0; off >>= 1)
#pragma unroll
      for (int r = 0; r < off; ++r) mx[r] = fmaxf(mx[r], mx[r + off]);
    float mc = fmaxf(mx[0], __shfl_xor(mx[0], 32, 64));
    float mj = fmaxf(m0, mc);
#pragma unroll
    for (int r = 0; r < 16; ++r) { a0[r] = exp2x(a0[r] - mj); a1[r] = exp2x(a1[r] - mj); }
    float sm[16];
#pragma unroll
    for (int r = 0; r < 16; ++r) sm[r] = a0[r] + a1[r];
#pragma unroll
    for (int off = 8; off > 0; off >>= 1)
#pragma unroll
      for (int r = 0; r < off; ++r) sm[r] += sm[r + off];
    float ssum = sm[0] + __shfl_xor(sm[0], 32, 64);
    float e0 = exp2x(m0 - mj);
    float den = S0 * e0 + ssum;
    float inv = rij / den;
    cacc += e0 * inv;
#pragma unroll
    for (int r = 0; r < 16; ++r) { a0[r] *= inv; a1[r] *= inv; }

    __builtin_amdgcn_s_setprio(1);
#pragma unroll
    for (int s = 0; s < 4; ++s) {
      bf16x8 wf = (s < 2) ? pack8v(a0, 8 * (s & 1)) : pack8v(a1, 8 * (s & 1));
      outAcc[0] = __builtin_amdgcn_mfma_f32_32x32x16_bf16(wf, vB[0][s], outAcc[0], 0, 0, 0);
      outAcc[1] = __builtin_amdgcn_mfma_f32_32x32x16_bf16(wf, vB[1][s], outAcc[1], 0, 0, 0);
    }
    __builtin_amdgcn_s_setprio(0);

    if (jj < 7) LOADG(vB, vbh + (size_t)(j + 4) * 4096);  // vB dead: prefetch
  }

  // ---- per-wave self term: out += cacc(row) * psA @ V_i ----
  {
    const u16* vib = vbh + (size_t)i * 4096;
    bf16x8 vBi[2][4];
    LOADG(vBi, vib);
    f32x16 U[2];
#pragma unroll
    for (int nv = 0; nv < 2; ++nv)
#pragma unroll
      for (int e = 0; e < 16; ++e) U[nv][e] = 0.f;
#pragma unroll
    for (int s = 0; s < 4; ++s) {
      U[0] = __builtin_amdgcn_mfma_f32_32x32x16_bf16(psA[s], vBi[0][s], U[0], 0, 0, 0);
      U[1] = __builtin_amdgcn_mfma_f32_32x32x16_bf16(psA[s], vBi[1][s], U[1], 0, 0, 0);
    }
    if (hi == 0) cbuf[w][l31] = cacc;
    __syncthreads();
#pragma unroll
    for (int r = 0; r < 16; ++r) {
      int row = (r & 3) + 8 * (r >> 2) + 4 * hi;
      float cr = cbuf[w][row];
      outAcc[0][r] += U[0][r] * cr;
      outAcc[1][r] += U[1][r] * cr;
    }
  }

  // ---- per-n 4-wave reduction tree ----
#define RED_W(buf)                                                         \
  {                                                                        \
    _Pragma("unroll") for (int ne = 0; ne < 2; ++ne)                       \
    _Pragma("unroll") for (int r = 0; r < 16; ++r) {                       \
      int row = (r & 3) + 8 * (r >> 2) + 4 * hi;                           \
      (buf)[row][l31 + 32 * ne] = outAcc[ne][r];                           \
    }                                                                      \
  }
#define RED_A(buf)                                                         \
  {                                                                        \
    _Pragma("unroll") for (int ne = 0; ne < 2; ++ne)                       \
    _Pragma("unroll") for (int r = 0; r < 16; ++r) {                       \
      int row = (r & 3) + 8 * (r >> 2) + 4 * hi;                           \
      outAcc[ne][r] += (buf)[row][l31 + 32 * ne];                          \
    }                                                                      \
  }

  if (g >= 2) RED_W(redh[n][g - 2]);
  __syncthreads();
  if (g < 2) RED_A(redh[n][g]);
  __syncthreads();
  if (g == 1) RED_W(redh[n][0]);
  __syncthreads();
  if (g == 0) {
    RED_A(redh[n][0]);
    RED_W(redh[n][0]);
  }
  __syncthreads();

  // coalesced store
  {
    int row = t >> 3;
    int nr = row >> 5, lrow = row & 31;
    int col0 = (t & 7) * 8;
    float4 a = *(const float4*)&redh[nr][0][lrow][col0];
    float4 b = *(const float4*)&redh[nr][0][lrow][col0 + 4];
    float* ob = out + ((size_t)bh * TT + i * SS + row) * DD + col0;
    *(float4*)ob = a;
    *(float4*)(ob + 4) = b;
  }
#undef LOADG
#undef RED_W
#undef RED_A
}

extern "C" void kernel_launch(void* const* d_in, const int* in_sizes, int n_in,
                              void* d_out, int out_size, void* d_ws, size_t ws_size,
                              hipStream_t stream) {
  (void)in_sizes; (void)n_in; (void)out_size; (void)ws_size;
  const float* q  = (const float*)d_in[0];
  const float* k  = (const float*)d_in[1];
  const float* v  = (const float*)d_in[2];
  const float* gu = (const float*)d_in[3];
  float* out = (float*)d_out;

  char* wsb = (char*)d_ws;
  u16* qb   = (u16*)(wsb);
  u16* kb   = (u16*)(wsb + (1 << 21));
  u16* vtb  = (u16*)(wsb + (2 << 21));
  float* qsum = (float*)(wsb + (3 << 21));
  float* ksum = (float*)(wsb + (3 << 21) + (1 << 16));

  prep_kernel<<<256, 256, 0, stream>>>(q, k, v, qb, kb, vtb, qsum, ksum);
  attn_kernel<<<BH * NB, 512, 0, stream>>>(qb, kb, vtb, qsum, ksum, gu, out);
}